// Round 1
// baseline (467.199 us; speedup 1.0000x reference)
//
#include <hip/hip_runtime.h>
#include <hip/hip_bf16.h>

#define BM 64
#define BN 64
#define DK 128
#define NSPLIT 4
#define BIGF 1e30f
#define MARGIN 0.3f

// Kernel 1: row squared norms. One wave (64 lanes) per row, D=128 -> 2 elems/lane.
__global__ void sqnorm_kernel(const float* __restrict__ x, float* __restrict__ sq, int N) {
    int wave = threadIdx.x >> 6;
    int lane = threadIdx.x & 63;
    int row = blockIdx.x * 4 + wave;
    if (row >= N) return;
    const float* xr = x + (size_t)row * DK;
    float v0 = xr[lane];
    float v1 = xr[lane + 64];
    float s = v0 * v0 + v1 * v1;
    #pragma unroll
    for (int o = 32; o > 0; o >>= 1) s += __shfl_xor(s, o, 64);
    if (lane == 0) sq[row] = s;
}

// Kernel 2: fused tiled dist + masked max/min.
// Grid: (N/BM, NSPLIT). Block: 256 threads as 16x16; each thread owns a 4x4 sub-tile.
__global__ __launch_bounds__(256, 1) void tile_kernel(
    const float* __restrict__ x, const int* __restrict__ lab,
    const float* __restrict__ sq,
    float* __restrict__ hp_part, float* __restrict__ hn_part, int N)
{
    // +1 pad: A-reads broadcast (4 distinct addrs, 16-lane broadcast each),
    // B-reads land 2-way per bank (free per m136).
    __shared__ float a_s[BM][DK + 1];
    __shared__ float b_s[BN][DK + 1];
    __shared__ int   lbl_s[BN];
    __shared__ float sqb_s[BN];
    __shared__ float red_hp[BM][16];
    __shared__ float red_hn[BM][16];

    const int tid = threadIdx.x;
    const int tx = tid & 15, ty = tid >> 4;
    const int rbase = blockIdx.x * BM;
    const int split = blockIdx.y;
    const int cols_per_split = N / NSPLIT;
    const int cbegin = split * cols_per_split;
    const int cend = cbegin + cols_per_split;

    // Load A tile once (scalar, coalesced, conflict-free LDS writes).
    for (int i = tid; i < BM * DK; i += 256) {
        int r = i >> 7, c = i & (DK - 1);
        a_s[r][c] = x[(size_t)(rbase + r) * DK + c];
    }

    int rlab[4]; float rsq[4];
    #pragma unroll
    for (int r = 0; r < 4; ++r) {
        int row = rbase + ty * 4 + r;
        rlab[r] = lab[row];
        rsq[r]  = sq[row];
    }
    float runhp[4], runhn[4];
    #pragma unroll
    for (int r = 0; r < 4; ++r) { runhp[r] = -BIGF; runhn[r] = BIGF; }

    for (int cbase = cbegin; cbase < cend; cbase += BN) {
        __syncthreads();  // previous iteration done reading b_s / sqb_s / lbl_s
        for (int i = tid; i < BN * DK; i += 256) {
            int r = i >> 7, c = i & (DK - 1);
            b_s[r][c] = x[(size_t)(cbase + r) * DK + c];
        }
        if (tid < BN) {
            lbl_s[tid] = lab[cbase + tid];
            sqb_s[tid] = sq[cbase + tid];
        }
        __syncthreads();

        float acc[4][4] = {};
        #pragma unroll 8
        for (int k = 0; k < DK; ++k) {
            float av[4], bv[4];
            #pragma unroll
            for (int r = 0; r < 4; ++r) av[r] = a_s[ty * 4 + r][k];
            #pragma unroll
            for (int c = 0; c < 4; ++c) bv[c] = b_s[tx * 4 + c][k];
            #pragma unroll
            for (int r = 0; r < 4; ++r)
                #pragma unroll
                for (int c = 0; c < 4; ++c)
                    acc[r][c] = fmaf(av[r], bv[c], acc[r][c]);
        }

        #pragma unroll
        for (int r = 0; r < 4; ++r) {
            int grow = rbase + ty * 4 + r;
            #pragma unroll
            for (int c = 0; c < 4; ++c) {
                int gcol = cbase + tx * 4 + c;
                float d2 = rsq[r] + sqb_s[tx * 4 + c] - 2.0f * acc[r][c];
                d2 = fmaxf(d2, 0.0f);
                float d = sqrtf(d2);
                bool same = (rlab[r] == lbl_s[tx * 4 + c]);
                if (same) {
                    if (grow != gcol) runhp[r] = fmaxf(runhp[r], d);
                } else {
                    runhn[r] = fminf(runhn[r], d);
                }
            }
        }
    }

    // Reduce the 16 tx-threads that share each row.
    __syncthreads();
    #pragma unroll
    for (int r = 0; r < 4; ++r) {
        red_hp[ty * 4 + r][tx] = runhp[r];
        red_hn[ty * 4 + r][tx] = runhn[r];
    }
    __syncthreads();
    if (tid < BM) {
        float hp = -BIGF, hn = BIGF;
        #pragma unroll
        for (int t = 0; t < 16; ++t) {
            hp = fmaxf(hp, red_hp[tid][t]);
            hn = fminf(hn, red_hn[tid][t]);
        }
        hp_part[(size_t)split * N + rbase + tid] = hp;
        hn_part[(size_t)split * N + rbase + tid] = hn;
    }
}

// Kernel 3: combine splits, per-row loss, mean over valid rows.
__global__ void finalize_kernel(const float* __restrict__ hp_part,
                                const float* __restrict__ hn_part,
                                float* __restrict__ out, int N)
{
    __shared__ float s_sum[256];
    __shared__ float s_cnt[256];
    int tid = threadIdx.x;
    float sum = 0.0f, cnt = 0.0f;
    for (int row = tid; row < N; row += 256) {
        float hp = -BIGF, hn = BIGF;
        #pragma unroll
        for (int s = 0; s < NSPLIT; ++s) {
            hp = fmaxf(hp, hp_part[(size_t)s * N + row]);
            hn = fminf(hn, hn_part[(size_t)s * N + row]);
        }
        bool valid = (hp > -0.5f * BIGF) && (hn < 0.5f * BIGF);
        if (valid) {
            sum += fmaxf(hp - hn + MARGIN, 0.0f);
            cnt += 1.0f;
        }
    }
    s_sum[tid] = sum; s_cnt[tid] = cnt;
    __syncthreads();
    for (int o = 128; o > 0; o >>= 1) {
        if (tid < o) { s_sum[tid] += s_sum[tid + o]; s_cnt[tid] += s_cnt[tid + o]; }
        __syncthreads();
    }
    if (tid == 0) out[0] = (s_cnt[0] > 0.0f) ? (s_sum[0] / s_cnt[0]) : 0.0f;
}

extern "C" void kernel_launch(void* const* d_in, const int* in_sizes, int n_in,
                              void* d_out, int out_size, void* d_ws, size_t ws_size,
                              hipStream_t stream) {
    const float* x = (const float*)d_in[0];
    const int* lab = (const int*)d_in[1];
    float* out = (float*)d_out;
    const int N = in_sizes[1];          // 8192
    // workspace layout: sq[N] | hp_part[NSPLIT*N] | hn_part[NSPLIT*N]
    float* sq = (float*)d_ws;
    float* hp_part = sq + N;
    float* hn_part = hp_part + (size_t)NSPLIT * N;

    sqnorm_kernel<<<N / 4, 256, 0, stream>>>(x, sq, N);
    dim3 grid(N / BM, NSPLIT);
    tile_kernel<<<grid, 256, 0, stream>>>(x, lab, sq, hp_part, hn_part, N);
    finalize_kernel<<<1, 256, 0, stream>>>(hp_part, hn_part, out, N);
}

// Round 2
// 133.126 us; speedup vs baseline: 3.5094x; 3.5094x over previous
//
#include <hip/hip_runtime.h>
#include <hip/hip_bf16.h>

#define NSPLIT 8
#define BIGF 1e30f
#define MARGIN 0.3f
#define DK 128
#define LDA 136   // padded LDS stride (bf16 elems): 272 B = 68 words, 16B-aligned, 2-way banks

typedef __attribute__((ext_vector_type(8))) short bf16x8;
typedef __attribute__((ext_vector_type(4))) float f32x4;

// Kernel 1: bf16 copy of X (row-major, RN rounding) + exact fp32 squared norms.
// One wave per row; lane handles 2 consecutive elements.
__global__ void prep_kernel(const float* __restrict__ x, ushort* __restrict__ xb,
                            float* __restrict__ sq, int N) {
    int wave = threadIdx.x >> 6;
    int lane = threadIdx.x & 63;
    int row = blockIdx.x * 4 + wave;
    if (row >= N) return;
    const float2* xr = (const float2*)(x + (size_t)row * DK);
    float2 v = xr[lane];
    __hip_bfloat16 b0 = __float2bfloat16(v.x);
    __hip_bfloat16 b1 = __float2bfloat16(v.y);
    ushort2 st;
    st.x = *(ushort*)&b0;
    st.y = *(ushort*)&b1;
    ((ushort2*)(xb + (size_t)row * DK))[lane] = st;
    float s = v.x * v.x + v.y * v.y;
    #pragma unroll
    for (int o = 32; o > 0; o >>= 1) s += __shfl_xor(s, o, 64);
    if (lane == 0) sq[row] = s;
}

// Kernel 2: fused bf16-MFMA dist^2 tile + masked max/min (d^2 domain).
// Grid (N/128, NSPLIT), 256 threads = 4 waves; wave w computes a 64x64 quadrant
// (wrow = (w>>1)*64, wcol = (w&1)*64) of each 128x128 tile.
__global__ __launch_bounds__(256, 2) void tile_kernel(
    const ushort* __restrict__ xb, const float* __restrict__ sq,
    const int* __restrict__ lab,
    float* __restrict__ hp_part, float* __restrict__ hn_part, int N)
{
    __shared__ ushort a_s[128 * LDA];
    __shared__ float sqa_s[128];
    __shared__ int   laba_s[128];
    __shared__ float red_hp[128][2];
    __shared__ float red_hn[128][2];

    const int tid  = threadIdx.x;
    const int lane = tid & 63;
    const int wave = tid >> 6;
    const int m16  = lane & 15;   // frag row (A/B); C col
    const int quad = lane >> 4;   // frag k-chunk; C row-group
    const int rbase = blockIdx.x * 128;
    const int wrow = (wave >> 1) * 64;
    const int wcol = (wave & 1) * 64;

    // Stage A tile (128x128 bf16) into padded LDS. 16B chunks, coalesced.
    for (int c = tid; c < 128 * 16; c += 256) {
        int r = c >> 4, c8 = c & 15;
        bf16x8 v = *(const bf16x8*)(xb + (size_t)(rbase + r) * DK + c8 * 8);
        *(bf16x8*)(a_s + r * LDA + c8 * 8) = v;
    }
    if (tid < 128) {
        sqa_s[tid]  = sq[rbase + tid];
        laba_s[tid] = lab[rbase + tid];
    }
    __syncthreads();

    float runhp[4][4], runhn[4][4];
    #pragma unroll
    for (int mt = 0; mt < 4; ++mt)
        #pragma unroll
        for (int r = 0; r < 4; ++r) { runhp[mt][r] = -BIGF; runhn[mt][r] = BIGF; }

    const int cols_per_split = N / NSPLIT;
    const int cbegin = blockIdx.y * cols_per_split;

    for (int ci = 0; ci < cols_per_split; ci += 128) {
        const int cbase = cbegin + ci;

        f32x4 acc[4][4];
        #pragma unroll
        for (int mt = 0; mt < 4; ++mt)
            #pragma unroll
            for (int nt = 0; nt < 4; ++nt)
                acc[mt][nt] = (f32x4){0.f, 0.f, 0.f, 0.f};

        #pragma unroll
        for (int s = 0; s < 4; ++s) {
            bf16x8 bfr[4], afr[4];
            #pragma unroll
            for (int nt = 0; nt < 4; ++nt)
                bfr[nt] = *(const bf16x8*)(xb + (size_t)(cbase + wcol + nt * 16 + m16) * DK
                                           + s * 32 + quad * 8);
            #pragma unroll
            for (int mt = 0; mt < 4; ++mt)
                afr[mt] = *(const bf16x8*)(a_s + (wrow + mt * 16 + m16) * LDA
                                           + s * 32 + quad * 8);
            #pragma unroll
            for (int mt = 0; mt < 4; ++mt)
                #pragma unroll
                for (int nt = 0; nt < 4; ++nt)
                    acc[mt][nt] = __builtin_amdgcn_mfma_f32_16x16x32_bf16(
                        afr[mt], bfr[nt], acc[mt][nt], 0, 0, 0);
        }

        // Epilogue: d^2 = sqa + sqb - 2*dot; masked running max/min in d^2 domain.
        #pragma unroll
        for (int nt = 0; nt < 4; ++nt) {
            int colg = cbase + wcol + nt * 16 + m16;
            float sqb = sq[colg];
            int lb = lab[colg];
            #pragma unroll
            for (int mt = 0; mt < 4; ++mt) {
                #pragma unroll
                for (int r = 0; r < 4; ++r) {
                    int rowl = wrow + mt * 16 + quad * 4 + r;
                    int rowg = rbase + rowl;
                    float d2 = sqa_s[rowl] + sqb - 2.0f * acc[mt][nt][r];
                    bool same = (laba_s[rowl] == lb);
                    bool diag = (rowg == colg);
                    runhp[mt][r] = fmaxf(runhp[mt][r], (same && !diag) ? d2 : -BIGF);
                    runhn[mt][r] = fminf(runhn[mt][r], same ? BIGF : d2);
                }
            }
        }
    }

    // Reduce across the 16 lanes (m16) that share each row.
    #pragma unroll
    for (int mt = 0; mt < 4; ++mt)
        #pragma unroll
        for (int r = 0; r < 4; ++r) {
            #pragma unroll
            for (int o = 8; o > 0; o >>= 1) {
                runhp[mt][r] = fmaxf(runhp[mt][r], __shfl_xor(runhp[mt][r], o, 16));
                runhn[mt][r] = fminf(runhn[mt][r], __shfl_xor(runhn[mt][r], o, 16));
            }
        }

    // Cross-wave combine: waves (wcol 0 / 64) pair up per row half.
    if (m16 == 0) {
        #pragma unroll
        for (int mt = 0; mt < 4; ++mt)
            #pragma unroll
            for (int r = 0; r < 4; ++r) {
                int rowl = wrow + mt * 16 + quad * 4 + r;
                red_hp[rowl][wave & 1] = runhp[mt][r];
                red_hn[rowl][wave & 1] = runhn[mt][r];
            }
    }
    __syncthreads();
    if (tid < 128) {
        float hp = fmaxf(red_hp[tid][0], red_hp[tid][1]);
        float hn = fminf(red_hn[tid][0], red_hn[tid][1]);
        hp_part[(size_t)blockIdx.y * N + rbase + tid] = hp;
        hn_part[(size_t)blockIdx.y * N + rbase + tid] = hn;
    }
}

// Kernel 3: combine splits, sqrt (monotone => commutes with max/min), mean loss.
__global__ void finalize_kernel(const float* __restrict__ hp_part,
                                const float* __restrict__ hn_part,
                                float* __restrict__ out, int N)
{
    __shared__ float s_sum[256];
    __shared__ float s_cnt[256];
    int tid = threadIdx.x;
    float sum = 0.0f, cnt = 0.0f;
    for (int row = tid; row < N; row += 256) {
        float hp = -BIGF, hn = BIGF;
        #pragma unroll
        for (int s = 0; s < NSPLIT; ++s) {
            hp = fmaxf(hp, hp_part[(size_t)s * N + row]);
            hn = fminf(hn, hn_part[(size_t)s * N + row]);
        }
        bool valid = (hp > -0.5f * BIGF) && (hn < 0.5f * BIGF);
        if (valid) {
            float dp = sqrtf(fmaxf(hp, 0.0f));
            float dn = sqrtf(fmaxf(hn, 0.0f));
            sum += fmaxf(dp - dn + MARGIN, 0.0f);
            cnt += 1.0f;
        }
    }
    s_sum[tid] = sum; s_cnt[tid] = cnt;
    __syncthreads();
    for (int o = 128; o > 0; o >>= 1) {
        if (tid < o) { s_sum[tid] += s_sum[tid + o]; s_cnt[tid] += s_cnt[tid + o]; }
        __syncthreads();
    }
    if (tid == 0) out[0] = (s_cnt[0] > 0.0f) ? (s_sum[0] / s_cnt[0]) : 0.0f;
}

extern "C" void kernel_launch(void* const* d_in, const int* in_sizes, int n_in,
                              void* d_out, int out_size, void* d_ws, size_t ws_size,
                              hipStream_t stream) {
    const float* x = (const float*)d_in[0];
    const int* lab = (const int*)d_in[1];
    float* out = (float*)d_out;
    const int N = in_sizes[1];          // 8192
    // ws layout: sq[N] f32 | hp_part[NSPLIT*N] | hn_part[NSPLIT*N] | xb[N*128] bf16
    float* sq = (float*)d_ws;
    float* hp_part = sq + N;
    float* hn_part = hp_part + (size_t)NSPLIT * N;
    ushort* xb = (ushort*)(hn_part + (size_t)NSPLIT * N);

    prep_kernel<<<N / 4, 256, 0, stream>>>(x, xb, sq, N);
    dim3 grid(N / 128, NSPLIT);
    tile_kernel<<<grid, 256, 0, stream>>>(xb, sq, lab, hp_part, hn_part, N);
    finalize_kernel<<<1, 256, 0, stream>>>(hp_part, hn_part, out, N);
}